// Round 3
// baseline (686.406 us; speedup 1.0000x reference)
//
#include <hip/hip_runtime.h>
#include <math.h>

#define Bc 64
#define Nc 4
#define Ac 1024
#define Oc 128
#define Dc 256
#define Qc 256
#define Hc 128
#define BN (Bc*Nc)

// ---- PROBE: repeat main body in-kernel to force it into the top-5 counter
// table (true dur/VGPR/occupancy/MfmaUtil/VALUBusy/bank-conflicts/FETCH).
// Deterministic: each rep recomputes identical values; last rep's results
// are what finalize consumes. Strip next round.
#define REP 10

using f4     = __attribute__((ext_vector_type(4))) float;
using f32x4  = __attribute__((ext_vector_type(4))) float;
using short8 = __attribute__((ext_vector_type(8))) short;
using us4    = __attribute__((ext_vector_type(4))) unsigned short;

__device__ inline float decode_t(const void* p) {
    int i = *(const int*)p;
    if (i >= 1 && i <= 1000000) return (float)i;
    return __int_as_float(i);
}

// round-to-nearest-even fp32 -> bf16
__device__ inline unsigned short bf16_rne(float x) {
    unsigned u = __builtin_bit_cast(unsigned, x);
    u += 0x7FFFu + ((u >> 16) & 1u);
    return (unsigned short)(u >> 16);
}

// split fp32 -> truncated bf16 hi + bf16(residual) lo.  x ~= hi + lo
__device__ inline void split_bf16(float x, unsigned short& hi, unsigned short& lo) {
    unsigned u = __builtin_bit_cast(unsigned, x);
    hi = (unsigned short)(u >> 16);
    float hif = __builtin_bit_cast(float, u & 0xFFFF0000u);
    float lof = x - hif;
    lo = (unsigned short)(__builtin_bit_cast(unsigned, lof) >> 16);
}

// ---------------------------------------------------------------------------
// prep_split: blocks 0..1023 split obj fp32 -> bf16 hi/lo (8 elems/thread);
// blocks 1024..1031 transpose+split W1[0:256][:] -> W1T hi/lo [128][256].
// ---------------------------------------------------------------------------
__global__ __launch_bounds__(256) void prep_split_kernel(
    const float* __restrict__ obj, const float* __restrict__ W1,
    unsigned short* __restrict__ obj_hi, unsigned short* __restrict__ obj_lo,
    unsigned short* __restrict__ W1T_hi, unsigned short* __restrict__ W1T_lo)
{
    __shared__ float Ts[64][65];
    const int t = threadIdx.x;
    const int bid = blockIdx.x;

    if (bid < 1024) {
        size_t i0 = ((size_t)bid * 256 + t) * 8;
        f4 v0 = *(const f4*)(obj + i0);
        f4 v1 = *(const f4*)(obj + i0 + 4);
        short8 hi, lo;
        unsigned short h16, l16;
        #pragma unroll
        for (int j = 0; j < 4; j++) {
            split_bf16(v0[j], h16, l16); hi[j] = (short)h16; lo[j] = (short)l16;
        }
        #pragma unroll
        for (int j = 0; j < 4; j++) {
            split_bf16(v1[j], h16, l16); hi[4 + j] = (short)h16; lo[4 + j] = (short)l16;
        }
        *(short8*)(obj_hi + i0) = hi;
        *(short8*)(obj_lo + i0) = lo;
    } else {
        const int wb = bid - 1024;            // 0..7
        const int d0 = (wb & 3) * 64, h0 = (wb >> 2) * 64;
        const int r4 = t >> 6, c = t & 63;
        #pragma unroll
        for (int rr = 0; rr < 16; rr++) {
            int d = rr * 4 + r4;
            Ts[d][c] = W1[(size_t)(d0 + d) * Hc + h0 + c];
        }
        __syncthreads();
        #pragma unroll
        for (int rr = 0; rr < 16; rr++) {
            int hl = rr * 4 + r4;
            float v = Ts[c][hl];              // = W1[d0+c][h0+hl]
            unsigned short h16, l16;
            split_bf16(v, h16, l16);
            W1T_hi[(size_t)(h0 + hl) * Dc + d0 + c] = h16;
            W1T_lo[(size_t)(h0 + hl) * Dc + d0 + c] = l16;
        }
    }
}

// ---------------------------------------------------------------------------
// prep_M2: Mt[b][h][o] = sum_d W1[d][h]*obj[b][o][d] via MFMA on split bf16.
// ---------------------------------------------------------------------------
__global__ __launch_bounds__(256, 4) void prep_M2_kernel(
    const unsigned short* __restrict__ W1T_hi, const unsigned short* __restrict__ W1T_lo,
    const unsigned short* __restrict__ obj_hi, const unsigned short* __restrict__ obj_lo,
    unsigned short* __restrict__ Mt_hi, unsigned short* __restrict__ Mt_lo)
{
    const int t = threadIdx.x;
    const int wave = t >> 6, lane = t & 63;
    const int l15 = lane & 15, quad = lane >> 4;
    const int h0 = blockIdx.x * 64 + wave * 16;
    const int o0 = blockIdx.y * 32;
    const int b  = blockIdx.z;

    const size_t arow  = (size_t)(h0 + l15) * Dc;
    const size_t brow0 = ((size_t)b * Oc + o0 + l15) * Dc;
    const size_t brow1 = ((size_t)b * Oc + o0 + 16 + l15) * Dc;

    f32x4 acc0 = (f32x4)(0.f), acc1 = (f32x4)(0.f);
    #pragma unroll
    for (int ks = 0; ks < 8; ks++) {
        const int ko = ks * 32 + quad * 8;
        short8 Ah  = *(const short8*)(W1T_hi + arow + ko);
        short8 Al  = *(const short8*)(W1T_lo + arow + ko);
        short8 B0h = *(const short8*)(obj_hi + brow0 + ko);
        short8 B0l = *(const short8*)(obj_lo + brow0 + ko);
        short8 B1h = *(const short8*)(obj_hi + brow1 + ko);
        short8 B1l = *(const short8*)(obj_lo + brow1 + ko);
        acc0 = __builtin_amdgcn_mfma_f32_16x16x32_bf16(Al, B0l, acc0, 0, 0, 0);
        acc0 = __builtin_amdgcn_mfma_f32_16x16x32_bf16(Al, B0h, acc0, 0, 0, 0);
        acc0 = __builtin_amdgcn_mfma_f32_16x16x32_bf16(Ah, B0l, acc0, 0, 0, 0);
        acc0 = __builtin_amdgcn_mfma_f32_16x16x32_bf16(Ah, B0h, acc0, 0, 0, 0);
        acc1 = __builtin_amdgcn_mfma_f32_16x16x32_bf16(Al, B1l, acc1, 0, 0, 0);
        acc1 = __builtin_amdgcn_mfma_f32_16x16x32_bf16(Al, B1h, acc1, 0, 0, 0);
        acc1 = __builtin_amdgcn_mfma_f32_16x16x32_bf16(Ah, B1l, acc1, 0, 0, 0);
        acc1 = __builtin_amdgcn_mfma_f32_16x16x32_bf16(Ah, B1h, acc1, 0, 0, 0);
    }

    #pragma unroll
    for (int r = 0; r < 4; r++) {
        int hrow = h0 + quad * 4 + r;
        size_t base = ((size_t)b * Hc + hrow) * Oc + o0 + l15;
        unsigned short hh, ll;
        split_bf16(acc0[r], hh, ll);
        Mt_hi[base] = hh; Mt_lo[base] = ll;
        split_bf16(acc1[r], hh, ll);
        Mt_hi[base + 16] = hh; Mt_lo[base + 16] = ll;
    }
}

// ---------------------------------------------------------------------------
// prep_qb: qb[bn,h] = q[bn,:] @ W1q + b1[h]
// ---------------------------------------------------------------------------
__global__ __launch_bounds__(512) void prep_qb_kernel(
    const float* __restrict__ q, const float* __restrict__ W1,
    const float* __restrict__ b1, float* __restrict__ qb)
{
    __shared__ float qs[256];
    __shared__ float red[4][128];
    const int t = threadIdx.x;
    const int bn = blockIdx.x;

    if (t < 256) qs[t] = q[bn * Qc + t];
    __syncthreads();

    const int h = t & 127, kq = t >> 7;
    float acc = 0.f;
    const float* w = W1 + (size_t)(Dc + kq * 64) * Hc + h;
    #pragma unroll 8
    for (int d = 0; d < 64; ++d)
        acc += qs[kq * 64 + d] * w[(size_t)d * Hc];
    red[kq][h] = acc;
    __syncthreads();

    if (t < 128)
        qb[bn * Hc + t] = b1[t] + red[0][t] + red[1][t] + red[2][t] + red[3][t];
}

// ---------------------------------------------------------------------------
// main_half: identical structure to R2, wrapped in a REP loop (probe).
// ---------------------------------------------------------------------------
__global__ __launch_bounds__(512, 4) void main_half_kernel(
    const float* __restrict__ att1, const int* __restrict__ tags,
    const unsigned short* __restrict__ Mt_hi, const unsigned short* __restrict__ Mt_lo,
    const float* __restrict__ qb, const float* __restrict__ W2,
    const float* __restrict__ b2, const void* __restrict__ tptr,
    float* __restrict__ out_part, float* __restrict__ z_part)
{
    __shared__ unsigned short A_s[64][136];   // bf16 tile for MFMA, 17.4 KB
    __shared__ float A32_s[64][132];          // fp32 tile for phase 3, 33.8 KB
    __shared__ float part2[64][9];            // logit partials, +1 pad
    __shared__ float part3[4][132];           // phase-3 partials
    __shared__ float e_s[64];
    __shared__ float qb_s[128], w2_s[128];

    const int t    = threadIdx.x;
    const int lane = t & 63;
    const int wave = t >> 6;          // 0..7
    const int l15  = lane & 15;
    const int quad = lane >> 4;
    const int blk  = blockIdx.x;      // 0..511
    const int bn   = blk >> 1;
    const int half = blk & 1;
    const int b    = bn >> 2;
    const int hw   = wave * 16;       // h-group base

    const float* att_half = att1 + ((size_t)bn * Ac + half * 512) * Oc;

    // ---- B fragments (hi/lo), once per block (rep-invariant) ----
    const size_t brow = ((size_t)b * Hc + hw + l15) * Oc;
    short8 Bh[4], Bl[4];
    #pragma unroll
    for (int ks = 0; ks < 4; ks++) {
        const int ko = ks * 32 + quad * 8;
        Bh[ks] = *(const short8*)(Mt_hi + brow + ko);
        Bl[ks] = *(const short8*)(Mt_lo + brow + ko);
    }
    if (t < 128) { qb_s[t] = qb[bn * Hc + t]; w2_s[t] = W2[t]; }
    const float b2v  = b2[0];
    const float tval = decode_t(tptr);

    for (int rep = 0; rep < REP; ++rep) {
        __syncthreads();

        // ---- prologue: tile-0 staging loads ----
        f4 sv[4];
        #pragma unroll
        for (int s = 0; s < 4; s++) {
            int idx = t + 512 * s;
            sv[s] = *(const f4*)(att_half + (size_t)idx * 4);
        }
        int tg_cur = (t < 64) ? tags[(size_t)bn * Ac + half * 512 + t] : 0;

        float z_reg = 0.f, out_reg = 0.f;

        for (int tile = 0; tile < 8; ++tile) {
            // ---- merged: reduce prev tile's part3; stage fp32+bf16 into LDS ----
            if (tile > 0 && t < 128) {
                float s = 0.f;
                #pragma unroll
                for (int g = 0; g < 4; g++) s += part3[g][t];
                out_reg += s;
            }
            #pragma unroll
            for (int s = 0; s < 4; s++) {
                int idx = t + 512 * s;
                int r = idx >> 5, c4 = idx & 31;
                us4 h4;
                #pragma unroll
                for (int j = 0; j < 4; j++) h4[j] = bf16_rne(sv[s][j]);
                *(us4*)&A_s[r][c4 * 4] = h4;
                *(f4*)&A32_s[r][c4 * 4] = sv[s];
            }
            __syncthreads();

            // ---- prefetch next tile ----
            int tg_next = 0;
            if (tile < 7) {
                const float* np = att_half + (size_t)(tile + 1) * 64 * Oc;
                #pragma unroll
                for (int s = 0; s < 4; s++) {
                    int idx = t + 512 * s;
                    sv[s] = *(const f4*)(np + (size_t)idx * 4);
                }
                if (t < 64) tg_next = tags[(size_t)bn * Ac + half * 512 + (tile + 1) * 64 + t];
            }

            // ---- MFMA: A_rne * (Bhi + Blo) ----
            f32x4 acc[4];
            #pragma unroll
            for (int i = 0; i < 4; i++) acc[i] = (f32x4)(0.f);
            #pragma unroll
            for (int ks = 0; ks < 4; ks++) {
                const int ko = ks * 32 + quad * 8;
                #pragma unroll
                for (int i = 0; i < 4; i++) {
                    short8 ah = *(const short8*)&A_s[i * 16 + l15][ko];
                    acc[i] = __builtin_amdgcn_mfma_f32_16x16x32_bf16(ah, Bh[ks], acc[i], 0, 0, 0);
                    acc[i] = __builtin_amdgcn_mfma_f32_16x16x32_bf16(ah, Bl[ks], acc[i], 0, 0, 0);
                }
            }

            // ---- epilogue: +qb, relu, *W2, reduce over the wave's 16 h ----
            {
                const float qbv = qb_s[hw + l15], w2v = w2_s[hw + l15];
                float p[4][4];
                #pragma unroll
                for (int i = 0; i < 4; i++)
                    #pragma unroll
                    for (int r = 0; r < 4; r++) {
                        float v = acc[i][r] + qbv;
                        v = v > 0.f ? v : 0.f;
                        p[i][r] = v * w2v;
                    }
                #pragma unroll
                for (int m = 1; m <= 8; m <<= 1)
                    #pragma unroll
                    for (int i = 0; i < 4; i++)
                        #pragma unroll
                        for (int r = 0; r < 4; r++)
                            p[i][r] += __shfl_xor(p[i][r], m);
                if (l15 == 0) {
                    #pragma unroll
                    for (int i = 0; i < 4; i++)
                        #pragma unroll
                        for (int r = 0; r < 4; r++)
                            part2[i * 16 + quad * 4 + r][wave] = p[i][r];
                }
            }
            __syncthreads();

            // ---- masked exp; accumulate Z (wave 0 only) ----
            if (t < 64) {
                float sum = b2v;
                #pragma unroll
                for (int x = 0; x < 8; x++) sum += part2[t][x];
                float logit = sum / tval;
                float e = (tg_cur > 0) ? __expf(logit) : 0.f;
                e_s[t] = e;
                z_reg += e;
            }
            __syncthreads();

            // ---- phase 3: partial out[o] += sum_a e[a]*A32[a,o] (pure LDS) ----
            {
                const int o = t & 127;
                const int g = t >> 7;   // 0..3, 16 rows each
                float accum = 0.f;
                #pragma unroll
                for (int a = 0; a < 16; a++)
                    accum += e_s[g * 16 + a] * A32_s[g * 16 + a][o];
                part3[g][o] = accum;
            }
            __syncthreads();
            tg_cur = tg_next;
        }

        // ---- finalize partials for this half (same values every rep) ----
        if (t < 128) {
            float s = 0.f;
            #pragma unroll
            for (int g = 0; g < 4; g++) s += part3[g][t];
            out_reg += s;
            out_part[(size_t)blk * 128 + t] = out_reg;
        }
        if (t < 64) {
            float z = z_reg;
            #pragma unroll
            for (int off = 32; off > 0; off >>= 1) z += __shfl_down(z, off);
            if (t == 0) z_part[blk] = z;
        }
    }
}

// ---------------------------------------------------------------------------
// finalize: out[bn,o] = (P0+P1)/(Z0+Z1)
// ---------------------------------------------------------------------------
__global__ __launch_bounds__(128) void finalize_kernel(
    const float* __restrict__ out_part, const float* __restrict__ z_part,
    float* __restrict__ out)
{
    const int bn = blockIdx.x;
    const int t  = threadIdx.x;
    const float Z = z_part[bn * 2] + z_part[bn * 2 + 1];
    const float v = out_part[(size_t)(bn * 2) * 128 + t]
                  + out_part[(size_t)(bn * 2 + 1) * 128 + t];
    out[(size_t)bn * 128 + t] = v / Z;
}

extern "C" void kernel_launch(void* const* d_in, const int* in_sizes, int n_in,
                              void* d_out, int out_size, void* d_ws, size_t ws_size,
                              hipStream_t stream)
{
    (void)in_sizes; (void)n_in; (void)out_size; (void)ws_size;

    const float* q    = (const float*)d_in[0];
    const float* att1 = (const float*)d_in[1];
    const float* obj  = (const float*)d_in[2];
    const int*   tags = (const int*)d_in[3];
    const float* W1   = (const float*)d_in[4];
    const float* b1   = (const float*)d_in[5];
    const float* W2   = (const float*)d_in[6];
    const float* b2   = (const float*)d_in[7];
    const void*  tptr = (const void*)d_in[8];
    float* out = (float*)d_out;

    char* wsb = (char*)d_ws;
    unsigned short* Mt_hi  = (unsigned short*)wsb;                           // 2 MB
    unsigned short* Mt_lo  = (unsigned short*)(wsb + (size_t) 2*1024*1024);  // 2 MB
    float* qbuf            = (float*)         (wsb + (size_t) 4*1024*1024);  // 128 KB
    float* out_part        = (float*)         (wsb + (size_t) 5*1024*1024);  // 256 KB
    float* z_part          = (float*)         (wsb + (size_t) 6*1024*1024);  // 2 KB
    unsigned short* W1T_hi = (unsigned short*)(wsb + (size_t) 7*1024*1024);  // 64 KB
    unsigned short* W1T_lo = (unsigned short*)(wsb + (size_t) 7*1024*1024 + 64*1024);
    unsigned short* obj_hi = (unsigned short*)(wsb + (size_t) 8*1024*1024);  // 4 MB
    unsigned short* obj_lo = (unsigned short*)(wsb + (size_t)12*1024*1024);  // 4 MB

    prep_split_kernel<<<dim3(1032), 256, 0, stream>>>(obj, W1, obj_hi, obj_lo,
                                                      W1T_hi, W1T_lo);
    prep_M2_kernel<<<dim3(2, 4, Bc), 256, 0, stream>>>(W1T_hi, W1T_lo, obj_hi, obj_lo,
                                                       Mt_hi, Mt_lo);
    prep_qb_kernel<<<dim3(BN), 512, 0, stream>>>(q, W1, b1, qbuf);
    main_half_kernel<<<dim3(2 * BN), 512, 0, stream>>>(att1, tags, Mt_hi, Mt_lo,
                                                       qbuf, W2, b2, tptr,
                                                       out_part, z_part);
    finalize_kernel<<<dim3(BN), 128, 0, stream>>>(out_part, z_part, out);
}

// Round 5
// 240.816 us; speedup vs baseline: 2.8503x; 2.8503x over previous
//
#include <hip/hip_runtime.h>
#include <math.h>

#define Bc 64
#define Nc 4
#define Ac 1024
#define Oc 128
#define Dc 256
#define Qc 256
#define Hc 128
#define BN (Bc*Nc)

using f4     = __attribute__((ext_vector_type(4))) float;
using f32x4  = __attribute__((ext_vector_type(4))) float;
using short8 = __attribute__((ext_vector_type(8))) short;
using us4    = __attribute__((ext_vector_type(4))) unsigned short;

__device__ inline float decode_t(const void* p) {
    int i = *(const int*)p;
    if (i >= 1 && i <= 1000000) return (float)i;
    return __int_as_float(i);
}

// round-to-nearest-even fp32 -> bf16
__device__ inline unsigned short bf16_rne(float x) {
    unsigned u = __builtin_bit_cast(unsigned, x);
    u += 0x7FFFu + ((u >> 16) & 1u);
    return (unsigned short)(u >> 16);
}

// split fp32 -> truncated bf16 hi + bf16(residual) lo.  x ~= hi + lo
__device__ inline void split_bf16(float x, unsigned short& hi, unsigned short& lo) {
    unsigned u = __builtin_bit_cast(unsigned, x);
    hi = (unsigned short)(u >> 16);
    float hif = __builtin_bit_cast(float, u & 0xFFFF0000u);
    float lof = x - hif;
    lo = (unsigned short)(__builtin_bit_cast(unsigned, lof) >> 16);
}

// VALU-only lane reduce within 16-lane rows via DPP row_ror (no LDS pipe).
// After 4 stages every lane in the 16-lane row holds the row sum.
template<int CTRL>
__device__ inline float dpp_ror_add(float x) {
    int yi = __builtin_amdgcn_update_dpp(0, __builtin_bit_cast(int, x),
                                         CTRL, 0xf, 0xf, true);
    return x + __builtin_bit_cast(float, yi);
}
__device__ inline float row16_sum(float v) {
    v = dpp_ror_add<0x128>(v);   // row_ror:8
    v = dpp_ror_add<0x124>(v);   // row_ror:4
    v = dpp_ror_add<0x122>(v);   // row_ror:2
    v = dpp_ror_add<0x121>(v);   // row_ror:1
    return v;
}

// ---------------------------------------------------------------------------
// prep_split: blocks 0..1023 split obj fp32 -> bf16 hi/lo (8 elems/thread);
// blocks 1024..1031 transpose+split W1[0:256][:] -> W1T hi/lo [128][256].
// ---------------------------------------------------------------------------
__global__ __launch_bounds__(256) void prep_split_kernel(
    const float* __restrict__ obj, const float* __restrict__ W1,
    unsigned short* __restrict__ obj_hi, unsigned short* __restrict__ obj_lo,
    unsigned short* __restrict__ W1T_hi, unsigned short* __restrict__ W1T_lo)
{
    __shared__ float Ts[64][65];
    const int t = threadIdx.x;
    const int bid = blockIdx.x;

    if (bid < 1024) {
        size_t i0 = ((size_t)bid * 256 + t) * 8;
        f4 v0 = *(const f4*)(obj + i0);
        f4 v1 = *(const f4*)(obj + i0 + 4);
        short8 hi, lo;
        unsigned short h16, l16;
        #pragma unroll
        for (int j = 0; j < 4; j++) {
            split_bf16(v0[j], h16, l16); hi[j] = (short)h16; lo[j] = (short)l16;
        }
        #pragma unroll
        for (int j = 0; j < 4; j++) {
            split_bf16(v1[j], h16, l16); hi[4 + j] = (short)h16; lo[4 + j] = (short)l16;
        }
        *(short8*)(obj_hi + i0) = hi;
        *(short8*)(obj_lo + i0) = lo;
    } else {
        const int wb = bid - 1024;            // 0..7
        const int d0 = (wb & 3) * 64, h0 = (wb >> 2) * 64;
        const int r4 = t >> 6, c = t & 63;
        #pragma unroll
        for (int rr = 0; rr < 16; rr++) {
            int d = rr * 4 + r4;
            Ts[d][c] = W1[(size_t)(d0 + d) * Hc + h0 + c];
        }
        __syncthreads();
        #pragma unroll
        for (int rr = 0; rr < 16; rr++) {
            int hl = rr * 4 + r4;
            float v = Ts[c][hl];              // = W1[d0+c][h0+hl]
            unsigned short h16, l16;
            split_bf16(v, h16, l16);
            W1T_hi[(size_t)(h0 + hl) * Dc + d0 + c] = h16;
            W1T_lo[(size_t)(h0 + hl) * Dc + d0 + c] = l16;
        }
    }
}

// ---------------------------------------------------------------------------
// prep_M2: Mt[b][h][o] = sum_d W1[d][h]*obj[b][o][d] via MFMA on split bf16.
// ---------------------------------------------------------------------------
__global__ __launch_bounds__(256, 4) void prep_M2_kernel(
    const unsigned short* __restrict__ W1T_hi, const unsigned short* __restrict__ W1T_lo,
    const unsigned short* __restrict__ obj_hi, const unsigned short* __restrict__ obj_lo,
    unsigned short* __restrict__ Mt_hi, unsigned short* __restrict__ Mt_lo)
{
    const int t = threadIdx.x;
    const int wave = t >> 6, lane = t & 63;
    const int l15 = lane & 15, quad = lane >> 4;
    const int h0 = blockIdx.x * 64 + wave * 16;
    const int o0 = blockIdx.y * 32;
    const int b  = blockIdx.z;

    const size_t arow  = (size_t)(h0 + l15) * Dc;
    const size_t brow0 = ((size_t)b * Oc + o0 + l15) * Dc;
    const size_t brow1 = ((size_t)b * Oc + o0 + 16 + l15) * Dc;

    f32x4 acc0 = (f32x4)(0.f), acc1 = (f32x4)(0.f);
    #pragma unroll
    for (int ks = 0; ks < 8; ks++) {
        const int ko = ks * 32 + quad * 8;
        short8 Ah  = *(const short8*)(W1T_hi + arow + ko);
        short8 Al  = *(const short8*)(W1T_lo + arow + ko);
        short8 B0h = *(const short8*)(obj_hi + brow0 + ko);
        short8 B0l = *(const short8*)(obj_lo + brow0 + ko);
        short8 B1h = *(const short8*)(obj_hi + brow1 + ko);
        short8 B1l = *(const short8*)(obj_lo + brow1 + ko);
        acc0 = __builtin_amdgcn_mfma_f32_16x16x32_bf16(Al, B0l, acc0, 0, 0, 0);
        acc0 = __builtin_amdgcn_mfma_f32_16x16x32_bf16(Al, B0h, acc0, 0, 0, 0);
        acc0 = __builtin_amdgcn_mfma_f32_16x16x32_bf16(Ah, B0l, acc0, 0, 0, 0);
        acc0 = __builtin_amdgcn_mfma_f32_16x16x32_bf16(Ah, B0h, acc0, 0, 0, 0);
        acc1 = __builtin_amdgcn_mfma_f32_16x16x32_bf16(Al, B1l, acc1, 0, 0, 0);
        acc1 = __builtin_amdgcn_mfma_f32_16x16x32_bf16(Al, B1h, acc1, 0, 0, 0);
        acc1 = __builtin_amdgcn_mfma_f32_16x16x32_bf16(Ah, B1l, acc1, 0, 0, 0);
        acc1 = __builtin_amdgcn_mfma_f32_16x16x32_bf16(Ah, B1h, acc1, 0, 0, 0);
    }

    #pragma unroll
    for (int r = 0; r < 4; r++) {
        int hrow = h0 + quad * 4 + r;
        size_t base = ((size_t)b * Hc + hrow) * Oc + o0 + l15;
        unsigned short hh, ll;
        split_bf16(acc0[r], hh, ll);
        Mt_hi[base] = hh; Mt_lo[base] = ll;
        split_bf16(acc1[r], hh, ll);
        Mt_hi[base + 16] = hh; Mt_lo[base + 16] = ll;
    }
}

// ---------------------------------------------------------------------------
// prep_qb: qb[bn,h] = q[bn,:] @ W1q + b1[h]
// ---------------------------------------------------------------------------
__global__ __launch_bounds__(512) void prep_qb_kernel(
    const float* __restrict__ q, const float* __restrict__ W1,
    const float* __restrict__ b1, float* __restrict__ qb)
{
    __shared__ float qs[256];
    __shared__ float red[4][128];
    const int t = threadIdx.x;
    const int bn = blockIdx.x;

    if (t < 256) qs[t] = q[bn * Qc + t];
    __syncthreads();

    const int h = t & 127, kq = t >> 7;
    float acc = 0.f;
    const float* w = W1 + (size_t)(Dc + kq * 64) * Hc + h;
    #pragma unroll 8
    for (int d = 0; d < 64; ++d)
        acc += qs[kq * 64 + d] * w[(size_t)d * Hc];
    red[kq][h] = acc;
    __syncthreads();

    if (t < 128)
        qb[bn * Hc + t] = b1[t] + red[0][t] + red[1][t] + red[2][t] + red[3][t];
}

// ---------------------------------------------------------------------------
// main_half: grid (512) = 2 blocks per bn, 512 thr, 2 blocks/CU.
// R3 probe verdict: LDS-pipe-bound (shfl_xor swizzles + scalar phase-3).
// R4: (1) epilogue reduce via DPP row_ror adds (VALU pipe, zero LDS traffic);
//     (2) phase-3 accumulates in registers across tiles (out4 per thread,
//         b128 LDS reads, no per-tile part3 write/merge).
// ---------------------------------------------------------------------------
__global__ __launch_bounds__(512, 4) void main_half_kernel(
    const float* __restrict__ att1, const int* __restrict__ tags,
    const unsigned short* __restrict__ Mt_hi, const unsigned short* __restrict__ Mt_lo,
    const float* __restrict__ qb, const float* __restrict__ W2,
    const float* __restrict__ b2, const void* __restrict__ tptr,
    float* __restrict__ out_part, float* __restrict__ z_part)
{
    __shared__ unsigned short A_s[64][136];   // bf16 tile for MFMA, 17.4 KB
    __shared__ float A32_s[64][132];          // fp32 tile for phase 3, 33.8 KB
    __shared__ float part2[64][9];            // logit partials, +1 pad
    __shared__ float part3[16][132];          // end-of-kernel o-reduce, 8.4 KB
    __shared__ float e_s[64];
    __shared__ float qb_s[128], w2_s[128];

    const int t    = threadIdx.x;
    const int lane = t & 63;
    const int wave = t >> 6;          // 0..7
    const int l15  = lane & 15;
    const int quad = lane >> 4;
    const int blk  = blockIdx.x;      // 0..511
    const int bn   = blk >> 1;
    const int half = blk & 1;
    const int b    = bn >> 2;
    const int hw   = wave * 16;       // h-group base
    const int g3   = t >> 5;          // phase-3 row group 0..15 (4 rows each)
    const int o4   = (t & 31) * 4;    // phase-3 o base (4 consecutive o)

    const float* att_half = att1 + ((size_t)bn * Ac + half * 512) * Oc;

    // ---- prologue: tile-0 staging loads (HBM) ----
    f4 sv[4];
    #pragma unroll
    for (int s = 0; s < 4; s++) {
        int idx = t + 512 * s;
        sv[s] = *(const f4*)(att_half + (size_t)idx * 4);
    }

    // ---- B fragments (hi/lo), once per block ----
    const size_t brow = ((size_t)b * Hc + hw + l15) * Oc;
    short8 Bh[4], Bl[4];
    #pragma unroll
    for (int ks = 0; ks < 4; ks++) {
        const int ko = ks * 32 + quad * 8;
        Bh[ks] = *(const short8*)(Mt_hi + brow + ko);
        Bl[ks] = *(const short8*)(Mt_lo + brow + ko);
    }

    if (t < 128) { qb_s[t] = qb[bn * Hc + t]; w2_s[t] = W2[t]; }
    int tg_cur = (t < 64) ? tags[(size_t)bn * Ac + half * 512 + t] : 0;
    const float b2v  = b2[0];
    const float tval = decode_t(tptr);

    float z_reg = 0.f;
    f4 out4 = {0.f, 0.f, 0.f, 0.f};   // this thread's out[o4..o4+3] partial

    for (int tile = 0; tile < 8; ++tile) {
        // ---- stage fp32+bf16 into LDS ----
        #pragma unroll
        for (int s = 0; s < 4; s++) {
            int idx = t + 512 * s;
            int r = idx >> 5, c4 = idx & 31;
            us4 h4;
            #pragma unroll
            for (int j = 0; j < 4; j++) h4[j] = bf16_rne(sv[s][j]);
            *(us4*)&A_s[r][c4 * 4] = h4;
            *(f4*)&A32_s[r][c4 * 4] = sv[s];
        }
        __syncthreads();

        // ---- prefetch next tile (in flight through all of this tile) ----
        int tg_next = 0;
        if (tile < 7) {
            const float* np = att_half + (size_t)(tile + 1) * 64 * Oc;
            #pragma unroll
            for (int s = 0; s < 4; s++) {
                int idx = t + 512 * s;
                sv[s] = *(const f4*)(np + (size_t)idx * 4);
            }
            if (t < 64) tg_next = tags[(size_t)bn * Ac + half * 512 + (tile + 1) * 64 + t];
        }

        // ---- MFMA: A_rne * (Bhi + Blo) ----
        f32x4 acc[4];
        #pragma unroll
        for (int i = 0; i < 4; i++) acc[i] = (f32x4)(0.f);
        #pragma unroll
        for (int ks = 0; ks < 4; ks++) {
            const int ko = ks * 32 + quad * 8;
            #pragma unroll
            for (int i = 0; i < 4; i++) {
                short8 ah = *(const short8*)&A_s[i * 16 + l15][ko];
                acc[i] = __builtin_amdgcn_mfma_f32_16x16x32_bf16(ah, Bh[ks], acc[i], 0, 0, 0);
                acc[i] = __builtin_amdgcn_mfma_f32_16x16x32_bf16(ah, Bl[ks], acc[i], 0, 0, 0);
            }
        }

        // ---- epilogue: +qb, relu, *W2; DPP row-reduce over the 16 h lanes ----
        // C/D layout: col(h) = l15, row(a) = i*16 + quad*4 + r
        {
            const float qbv = qb_s[hw + l15], w2v = w2_s[hw + l15];
            #pragma unroll
            for (int i = 0; i < 4; i++)
                #pragma unroll
                for (int r = 0; r < 4; r++) {
                    float v = acc[i][r] + qbv;
                    v = v > 0.f ? v : 0.f;
                    float s = row16_sum(v * w2v);   // VALU DPP, no LDS
                    if (l15 == 0)
                        part2[i * 16 + quad * 4 + r][wave] = s;
                }
        }
        __syncthreads();

        // ---- masked exp; accumulate Z in registers (wave 0 only) ----
        if (t < 64) {
            float sum = b2v;
            #pragma unroll
            for (int x = 0; x < 8; x++) sum += part2[t][x];
            float logit = sum / tval;
            float e = (tg_cur > 0) ? __expf(logit) : 0.f;
            e_s[t] = e;
            z_reg += e;
        }
        __syncthreads();

        // ---- phase 3: out4 += sum_a e[a]*A32[a, o4..o4+3]  (regs, b128) ----
        #pragma unroll
        for (int a = 0; a < 4; a++) {
            const int row = g3 * 4 + a;
            const float ev = e_s[row];
            f4 v = *(const f4*)&A32_s[row][o4];
            out4[0] += ev * v[0];
            out4[1] += ev * v[1];
            out4[2] += ev * v[2];
            out4[3] += ev * v[3];
        }
        __syncthreads();
        tg_cur = tg_next;
    }

    // ---- finalize: one part3 write + reduce, z reduce, store ----
    *(f4*)&part3[g3][o4] = out4;
    __syncthreads();
    if (t < 128) {
        float s = 0.f;
        #pragma unroll
        for (int g = 0; g < 16; g++) s += part3[g][t];
        out_part[(size_t)blk * 128 + t] = s;
    }
    if (t < 64) {   // all z_reg live in wave 0
        float z = z_reg;
        #pragma unroll
        for (int off = 32; off > 0; off >>= 1) z += __shfl_down(z, off);
        if (t == 0) z_part[blk] = z;
    }
}

// ---------------------------------------------------------------------------
// finalize: out[bn,o] = (P0+P1)/(Z0+Z1)
// ---------------------------------------------------------------------------
__global__ __launch_bounds__(128) void finalize_kernel(
    const float* __restrict__ out_part, const float* __restrict__ z_part,
    float* __restrict__ out)
{
    const int bn = blockIdx.x;
    const int t  = threadIdx.x;
    const float Z = z_part[bn * 2] + z_part[bn * 2 + 1];
    const float v = out_part[(size_t)(bn * 2) * 128 + t]
                  + out_part[(size_t)(bn * 2 + 1) * 128 + t];
    out[(size_t)bn * 128 + t] = v / Z;
}

extern "C" void kernel_launch(void* const* d_in, const int* in_sizes, int n_in,
                              void* d_out, int out_size, void* d_ws, size_t ws_size,
                              hipStream_t stream)
{
    (void)in_sizes; (void)n_in; (void)out_size; (void)ws_size;

    const float* q    = (const float*)d_in[0];
    const float* att1 = (const float*)d_in[1];
    const float* obj  = (const float*)d_in[2];
    const int*   tags = (const int*)d_in[3];
    const float* W1   = (const float*)d_in[4];
    const float* b1   = (const float*)d_in[5];
    const float* W2   = (const float*)d_in[6];
    const float* b2   = (const float*)d_in[7];
    const void*  tptr = (const void*)d_in[8];
    float* out = (float*)d_out;

    char* wsb = (char*)d_ws;
    unsigned short* Mt_hi  = (unsigned short*)wsb;                           // 2 MB
    unsigned short* Mt_lo  = (unsigned short*)(wsb + (size_t) 2*1024*1024);  // 2 MB
    float* qbuf            = (float*)         (wsb + (size_t) 4*1024*1024);  // 128 KB
    float* out_part        = (float*)         (wsb + (size_t) 5*1024*1024);  // 256 KB
    float* z_part          = (float*)         (wsb + (size_t) 6*1024*1024);  // 2 KB
    unsigned short* W1T_hi = (unsigned short*)(wsb + (size_t) 7*1024*1024);  // 64 KB
    unsigned short* W1T_lo = (unsigned short*)(wsb + (size_t) 7*1024*1024 + 64*1024);
    unsigned short* obj_hi = (unsigned short*)(wsb + (size_t) 8*1024*1024);  // 4 MB
    unsigned short* obj_lo = (unsigned short*)(wsb + (size_t)12*1024*1024);  // 4 MB

    prep_split_kernel<<<dim3(1032), 256, 0, stream>>>(obj, W1, obj_hi, obj_lo,
                                                      W1T_hi, W1T_lo);
    prep_M2_kernel<<<dim3(2, 4, Bc), 256, 0, stream>>>(W1T_hi, W1T_lo, obj_hi, obj_lo,
                                                       Mt_hi, Mt_lo);
    prep_qb_kernel<<<dim3(BN), 512, 0, stream>>>(q, W1, b1, qbuf);
    main_half_kernel<<<dim3(2 * BN), 512, 0, stream>>>(att1, tags, Mt_hi, Mt_lo,
                                                       qbuf, W2, b2, tptr,
                                                       out_part, z_part);
    finalize_kernel<<<dim3(BN), 128, 0, stream>>>(out_part, z_part, out);
}